// Round 4
// baseline (3361.086 us; speedup 1.0000x reference)
//
#include <hip/hip_runtime.h>

#define D 32
#define RB 512            // rows per destination bucket
#define RB_SHIFT 9
#define MAXNB 4096        // max buckets supported by hist LDS / scan (N2 <= 2M)

// ---------------------------------------------------------------------------
__global__ __launch_bounds__(256) void zero_i32(int* __restrict__ p, int n) {
    int i = blockIdx.x * blockDim.x + threadIdx.x;
    int stride = gridDim.x * blockDim.x;
    for (; i < n; i += stride) p[i] = 0;
}

// ---------------------------------------------------------------------------
// per-bucket histogram of entries (2 per edge), LDS-binned to tame contention
// ---------------------------------------------------------------------------
__global__ __launch_bounds__(256) void bucket_hist(
        const int* __restrict__ src, const int* __restrict__ dst,
        int* __restrict__ bcnt, int NU, int E, int nb) {
    __shared__ int h[MAXNB];
    for (int i = threadIdx.x; i < nb; i += 256) h[i] = 0;
    __syncthreads();
    int i = blockIdx.x * 256 + threadIdx.x;
    int stride = gridDim.x * 256;
    for (; i < E; i += stride) {
        int s = src[i];
        int d = dst[i];
        atomicAdd(&h[s >> RB_SHIFT], 1);
        atomicAdd(&h[(NU + d) >> RB_SHIFT], 1);
    }
    __syncthreads();
    for (int j = threadIdx.x; j < nb; j += 256)
        if (h[j]) atomicAdd(&bcnt[j], h[j]);
}

// ---------------------------------------------------------------------------
// exclusive scan of <=4096 bucket counts, one block of 1024 threads (4 each)
// ---------------------------------------------------------------------------
__global__ __launch_bounds__(1024) void scan_buckets(
        const int* __restrict__ bcnt, int* __restrict__ boffs,
        int* __restrict__ bcursor, int nb) {
    __shared__ int s[1024];
    int t = threadIdx.x;
    int x[4], pre[4], sum = 0;
#pragma unroll
    for (int j = 0; j < 4; ++j) {
        int g = t * 4 + j;
        x[j] = (g < nb) ? bcnt[g] : 0;
        pre[j] = sum;
        sum += x[j];
    }
    s[t] = sum;
    __syncthreads();
    for (int off = 1; off < 1024; off <<= 1) {
        int v = (t >= off) ? s[t - off] : 0;
        __syncthreads();
        s[t] += v;
        __syncthreads();
    }
    int prefix = (t == 0) ? 0 : s[t - 1];
#pragma unroll
    for (int j = 0; j < 4; ++j) {
        int g = t * 4 + j;
        if (g < nb) {
            int o = prefix + pre[j];
            boffs[g] = o;
            bcursor[g] = o;
            if (g == nb - 1) boffs[nb] = o + x[j];
        }
    }
}

// ---------------------------------------------------------------------------
// partition: per edge, append one packed entry per direction to the dst
// bucket. entry = (rowLocal<<20) | nbrIdx  (rowLocal<512, nbrIdx<2^20).
// Writes within a bucket are sequential -> L2-absorbed (~250KB active lines).
// ---------------------------------------------------------------------------
__global__ __launch_bounds__(256) void partition(
        const int* __restrict__ src, const int* __restrict__ dst,
        int* __restrict__ bcursor, unsigned int* __restrict__ ents,
        int NU, int E) {
    int i = blockIdx.x * 256 + threadIdx.x;
    int stride = gridDim.x * 256;
    for (; i < E; i += stride) {
        int s = src[i];
        int d = dst[i];
        // user row s aggregates item d
        int p1 = atomicAdd(&bcursor[s >> RB_SHIFT], 1);
        ents[p1] = ((unsigned)(s & (RB - 1)) << 20) | (unsigned)d;
        // item row NU+d aggregates user s
        int r2 = NU + d;
        int p2 = atomicAdd(&bcursor[r2 >> RB_SHIFT], 1);
        ents[p2] = ((unsigned)(r2 & (RB - 1)) << 20) | (unsigned)s;
    }
}

// ---------------------------------------------------------------------------
// fused per-bucket aggregate + SAGE transform. One block per bucket of 512
// combined rows. LDS 512x32 f32 accumulator + counts; coalesced entry reads;
// 8-deep independent 128B gathers per 32-lane group; LDS atomic accumulate;
// then mean + self@Wself + mean@Wneigh + b, one coalesced output write/row.
// ---------------------------------------------------------------------------
__global__ __launch_bounds__(256, 2) void sage_bucket(
        const float* __restrict__ ue, const float* __restrict__ ie,
        const unsigned int* __restrict__ ents, const int* __restrict__ boffs,
        const float* __restrict__ Ws, const float* __restrict__ Wn,
        const float* __restrict__ bias,
        float* __restrict__ out, long NU, long N2) {
    __shared__ float sacc[RB * D];           // 64 KB
    __shared__ int   scnt[RB];               // 2 KB
    __shared__ float sWs[D * D], sWn[D * D], sb2[D];  // 8.25 KB
    int tid = threadIdx.x;
    for (int i = tid; i < D * D; i += 256) {
        sWs[i] = Ws[i];
        sWn[i] = Wn[i];
    }
    if (tid < D) sb2[tid] = bias[tid];
    for (int i = tid; i < RB * D; i += 256) sacc[i] = 0.f;
    for (int i = tid; i < RB; i += 256) scnt[i] = 0;
    __syncthreads();

    int b = blockIdx.x;
    int e0 = boffs[b];
    int e1 = boffs[b + 1];
    int gid = tid >> 5;
    int lane = tid & 31;
    long rowbase = (long)b << RB_SHIFT;

    for (int base = e0 + gid * 8; base < e1; base += 64) {
        int n = e1 - base;
        if (n > 8) n = 8;
        unsigned en[8];
        float v[8];
#pragma unroll
        for (int u = 0; u < 8; ++u) {
            int uu = u < n ? u : n - 1;          // clamp tail (dup loads cache-hit)
            en[u] = ents[base + uu];
        }
#pragma unroll
        for (int u = 0; u < 8; ++u) {
            unsigned nbr = en[u] & 0xFFFFFu;
            unsigned rl  = en[u] >> 20;
            const float* tab = (rowbase + rl < NU) ? ie : ue;
            v[u] = tab[(long)nbr * D + lane];    // coalesced 128B row gather
        }
#pragma unroll
        for (int u = 0; u < 8; ++u) {
            if (u < n) {
                unsigned rl = en[u] >> 20;
                atomicAdd(&sacc[rl * D + lane], v[u]);
                if (lane == 0) atomicAdd(&scnt[rl], 1);
            }
        }
    }
    __syncthreads();

    for (int r = gid; r < RB; r += 8) {
        long row = rowbase + r;
        if (row >= N2) break;
        float m = sacc[r * D + lane] / fmaxf((float)scnt[r], 1.f);
        const float* self = (row < NU) ? (ue + row * D) : (ie + (row - NU) * D);
        float e = self[lane];
        float acc = sb2[lane];
#pragma unroll
        for (int k = 0; k < D; ++k) {
            acc += __shfl(e, k, 32) * sWs[k * D + lane]
                 + __shfl(m, k, 32) * sWn[k * D + lane];
        }
        out[row * D + lane] = acc;   // item_out is contiguous after user_out
    }
}

// ---------------------------------------------------------------------------
extern "C" void kernel_launch(void* const* d_in, const int* in_sizes, int n_in,
                              void* d_out, int out_size, void* d_ws, size_t ws_size,
                              hipStream_t stream) {
    const float* user_embed = (const float*)d_in[0];
    const float* item_embed = (const float*)d_in[1];
    const float* W_self     = (const float*)d_in[2];
    const float* W_neigh    = (const float*)d_in[3];
    const float* bias       = (const float*)d_in[4];
    const int*   edge_src   = (const int*)d_in[5];
    const int*   edge_dst   = (const int*)d_in[6];

    const int NU = in_sizes[0] / D;
    const int NI = in_sizes[1] / D;
    const int E  = in_sizes[5];
    const long N2 = (long)NU + NI;
    const int nb = (int)((N2 + RB - 1) >> RB_SHIFT);   // 3907 for 2M rows

    float* out = (float*)d_out;   // [NU*D] user rows then [NI*D] item rows

    // workspace (ints): bcnt[nb] | boffs[nb+1] | bcursor[nb] | ents[2E]
    int* bcnt    = (int*)d_ws;
    int* boffs   = bcnt + nb;
    int* bcursor = boffs + nb + 1;
    unsigned int* ents = (unsigned int*)(bcursor + nb);

    // 1) zero bucket counts
    zero_i32<<<16, 256, 0, stream>>>(bcnt, nb);

    // 2) per-bucket entry histogram
    bucket_hist<<<512, 256, 0, stream>>>(edge_src, edge_dst, bcnt, NU, E, nb);

    // 3) exclusive scan -> boffs + cursor copy
    scan_buckets<<<1, 1024, 0, stream>>>(bcnt, boffs, bcursor, nb);

    // 4) partition packed entries into buckets (locality-friendly writes)
    partition<<<2048, 256, 0, stream>>>(edge_src, edge_dst, bcursor, ents, NU, E);

    // 5) fused per-bucket aggregate + transform (one block per bucket)
    sage_bucket<<<nb, 256, 0, stream>>>(user_embed, item_embed, ents, boffs,
                                        W_self, W_neigh, bias, out, NU, N2);
}

// Round 5
// 2074.812 us; speedup vs baseline: 1.6199x; 1.6199x over previous
//
#include <hip/hip_runtime.h>

#define D 32
#define RB 512            // rows per destination bucket
#define RB_SHIFT 9
#define MAXNB 4096        // max buckets (N2 <= 2M with RB=512)

// ---------------------------------------------------------------------------
__global__ __launch_bounds__(256) void zero_i32(int* __restrict__ p, int n) {
    int i = blockIdx.x * blockDim.x + threadIdx.x;
    int stride = gridDim.x * blockDim.x;
    for (; i < n; i += stride) p[i] = 0;
}

// ---------------------------------------------------------------------------
// per-bucket histogram of entries (2 per edge), LDS-binned
// ---------------------------------------------------------------------------
__global__ __launch_bounds__(256) void bucket_hist(
        const int* __restrict__ src, const int* __restrict__ dst,
        int* __restrict__ bcnt, int NU, int E, int nb) {
    __shared__ int h[MAXNB];
    for (int i = threadIdx.x; i < nb; i += 256) h[i] = 0;
    __syncthreads();
    int i = blockIdx.x * 256 + threadIdx.x;
    int stride = gridDim.x * 256;
    for (; i < E; i += stride) {
        int s = src[i];
        int d = dst[i];
        atomicAdd(&h[s >> RB_SHIFT], 1);
        atomicAdd(&h[(NU + d) >> RB_SHIFT], 1);
    }
    __syncthreads();
    for (int j = threadIdx.x; j < nb; j += 256)
        if (h[j]) atomicAdd(&bcnt[j], h[j]);
}

// ---------------------------------------------------------------------------
// exclusive scan of <=4096 bucket counts, one block of 1024 threads (4 each)
// ---------------------------------------------------------------------------
__global__ __launch_bounds__(1024) void scan_buckets(
        const int* __restrict__ bcnt, int* __restrict__ boffs,
        int* __restrict__ bcursor, int nb) {
    __shared__ int s[1024];
    int t = threadIdx.x;
    int x[4], pre[4], sum = 0;
#pragma unroll
    for (int j = 0; j < 4; ++j) {
        int g = t * 4 + j;
        x[j] = (g < nb) ? bcnt[g] : 0;
        pre[j] = sum;
        sum += x[j];
    }
    s[t] = sum;
    __syncthreads();
    for (int off = 1; off < 1024; off <<= 1) {
        int v = (t >= off) ? s[t - off] : 0;
        __syncthreads();
        s[t] += v;
        __syncthreads();
    }
    int prefix = (t == 0) ? 0 : s[t - 1];
#pragma unroll
    for (int j = 0; j < 4; ++j) {
        int g = t * 4 + j;
        if (g < nb) {
            int o = prefix + pre[j];
            boffs[g] = o;
            bcursor[g] = o;
            if (g == nb - 1) boffs[nb] = o + x[j];
        }
    }
}

// ---------------------------------------------------------------------------
// partition: per edge, append one packed entry per direction to the dst
// bucket. entry = (rowLocal<<20) | nbrIdx (rowLocal<512, nbrIdx<2^20).
// Bucket-sequential writes -> active line set ~250KB -> L2-absorbed.
// ---------------------------------------------------------------------------
__global__ __launch_bounds__(256) void partition(
        const int* __restrict__ src, const int* __restrict__ dst,
        int* __restrict__ bcursor, unsigned int* __restrict__ ents,
        int NU, int E) {
    int i = blockIdx.x * 256 + threadIdx.x;
    int stride = gridDim.x * 256;
    for (; i < E; i += stride) {
        int s = src[i];
        int d = dst[i];
        int p1 = atomicAdd(&bcursor[s >> RB_SHIFT], 1);
        ents[p1] = ((unsigned)(s & (RB - 1)) << 20) | (unsigned)d;
        int r2 = NU + d;
        int p2 = atomicAdd(&bcursor[r2 >> RB_SHIFT], 1);
        ents[p2] = ((unsigned)(r2 & (RB - 1)) << 20) | (unsigned)s;
    }
}

// ---------------------------------------------------------------------------
// block-local counting sort: bucket entries -> row-ordered CSR + per-row offs.
// All reads/writes confined to the bucket's contiguous window (L2-friendly).
// ---------------------------------------------------------------------------
__global__ __launch_bounds__(256) void local_sort(
        const unsigned int* __restrict__ ents, const int* __restrict__ boffs,
        int* __restrict__ csr, int* __restrict__ offs, long N2, int nb) {
    __shared__ int cnt[RB];
    __shared__ int cur[RB];
    __shared__ int tsum[256];
    int b = blockIdx.x, t = threadIdx.x;
    int e0 = boffs[b], e1 = boffs[b + 1];
    cnt[t] = 0;
    cnt[t + 256] = 0;
    __syncthreads();
    for (int i = e0 + t; i < e1; i += 256)
        atomicAdd(&cnt[ents[i] >> 20], 1);
    __syncthreads();
    int a0 = cnt[2 * t], a1 = cnt[2 * t + 1];
    tsum[t] = a0 + a1;
    __syncthreads();
    for (int off = 1; off < 256; off <<= 1) {
        int v = (t >= off) ? tsum[t - off] : 0;
        __syncthreads();
        tsum[t] += v;
        __syncthreads();
    }
    int pre = (t == 0) ? 0 : tsum[t - 1];
    cur[2 * t]     = pre;
    cur[2 * t + 1] = pre + a0;
    long rowbase = (long)b << RB_SHIFT;
    if (rowbase + 2 * t < N2)     offs[rowbase + 2 * t]     = e0 + pre;
    if (rowbase + 2 * t + 1 < N2) offs[rowbase + 2 * t + 1] = e0 + pre + a0;
    if (b == nb - 1 && t == 0)    offs[N2] = e1;
    __syncthreads();
    for (int i = e0 + t; i < e1; i += 256) {
        unsigned en = ents[i];
        int rl = (int)(en >> 20);
        int pos = atomicAdd(&cur[rl], 1);
        csr[e0 + pos] = (int)(en & 0xFFFFFu);
    }
}

// ---------------------------------------------------------------------------
// one phase of fused aggregate + SAGE transform (dst rows gather from one
// source table, which stays L3-resident for the whole dispatch).
// One 32-lane group per row; batched index loads; 8-deep independent gathers.
// ---------------------------------------------------------------------------
__global__ __launch_bounds__(256, 8) void sage_phase(
        const float* __restrict__ self_embed,
        const float* __restrict__ nbr_embed,
        const int* __restrict__ offs,      // [N+1], pre-offset for this phase
        const int* __restrict__ csr,
        const float* __restrict__ Wself, const float* __restrict__ Wneigh,
        const float* __restrict__ bias,
        float* __restrict__ out, int N) {
    __shared__ float sWs[D * D];
    __shared__ float sWn[D * D];
    __shared__ float sb[D];
    for (int i = threadIdx.x; i < D * D; i += blockDim.x) {
        sWs[i] = Wself[i];
        sWn[i] = Wneigh[i];
    }
    if (threadIdx.x < D) sb[threadIdx.x] = bias[threadIdx.x];
    __syncthreads();

    int lane = threadIdx.x & 31;
    long g  = ((long)blockIdx.x * blockDim.x + threadIdx.x) >> 5;
    long ng = ((long)gridDim.x * blockDim.x) >> 5;

    for (long row = g; row < N; row += ng) {
        int o0 = offs[row];
        int o1 = offs[row + 1];
        int deg = o1 - o0;
        float s = 0.f;
        for (int j0 = o0; j0 < o1; j0 += 32) {
            int nb = o1 - j0;
            if (nb > 32) nb = 32;
            int idx = csr[j0 + (lane < nb ? lane : nb - 1)];
            for (int k = 0; k < nb; k += 8) {
                int kr = nb - k;  // >= 1
                float v[8];
#pragma unroll
                for (int u = 0; u < 8; ++u) {
                    int uu = u < kr ? u : kr - 1;   // clamp (dup loads cache-hit)
                    int bi = __shfl(idx, k + uu, 32);
                    v[u] = nbr_embed[(long)bi * D + lane];
                }
#pragma unroll
                for (int u = 0; u < 8; ++u) {
                    s += (u < kr) ? v[u] : 0.f;
                }
            }
        }
        float m = s / fmaxf((float)deg, 1.0f);
        float e = self_embed[row * D + lane];
        float acc = sb[lane];
#pragma unroll
        for (int k = 0; k < D; ++k) {
            acc += __shfl(e, k, 32) * sWs[k * D + lane]
                 + __shfl(m, k, 32) * sWn[k * D + lane];
        }
        out[row * D + lane] = acc;
    }
}

// ---------------------------------------------------------------------------
extern "C" void kernel_launch(void* const* d_in, const int* in_sizes, int n_in,
                              void* d_out, int out_size, void* d_ws, size_t ws_size,
                              hipStream_t stream) {
    const float* user_embed = (const float*)d_in[0];
    const float* item_embed = (const float*)d_in[1];
    const float* W_self     = (const float*)d_in[2];
    const float* W_neigh    = (const float*)d_in[3];
    const float* bias       = (const float*)d_in[4];
    const int*   edge_src   = (const int*)d_in[5];
    const int*   edge_dst   = (const int*)d_in[6];

    const int NU = in_sizes[0] / D;
    const int NI = in_sizes[1] / D;
    const int E  = in_sizes[5];
    const long N2 = (long)NU + NI;
    const int nb = (int)((N2 + RB - 1) >> RB_SHIFT);   // 3907 for 2M rows

    float* user_out = (float*)d_out;            // [NU*D]
    float* item_out = user_out + (long)NU * D;  // [NI*D]

    // workspace (ints): bcnt[nb] | boffs[nb+1] | bcursor[nb] | offs[N2+1] |
    //                   ents[2E] | csr[2E]
    int* bcnt    = (int*)d_ws;
    int* boffs   = bcnt + nb;
    int* bcursor = boffs + nb + 1;
    int* offs    = bcursor + nb;
    unsigned int* ents = (unsigned int*)(offs + N2 + 1);
    int* csr     = (int*)(ents + 2L * E);

    // 1) zero bucket counts
    zero_i32<<<16, 256, 0, stream>>>(bcnt, nb);

    // 2) per-bucket entry histogram
    bucket_hist<<<512, 256, 0, stream>>>(edge_src, edge_dst, bcnt, NU, E, nb);

    // 3) exclusive scan -> boffs + cursor copy
    scan_buckets<<<1, 1024, 0, stream>>>(bcnt, boffs, bcursor, nb);

    // 4) partition packed entries into buckets (bucket-sequential writes)
    partition<<<2048, 256, 0, stream>>>(edge_src, edge_dst, bcursor, ents, NU, E);

    // 5) block-local counting sort -> row-ordered CSR + per-row offs
    local_sort<<<nb, 256, 0, stream>>>(ents, boffs, csr, offs, N2, nb);

    // 6) fused gather-mean + SAGE transform, phase-split for L3 residency
    sage_phase<<<2048, 256, 0, stream>>>(user_embed, item_embed, offs, csr,
                                         W_self, W_neigh, bias, user_out, NU);
    sage_phase<<<2048, 256, 0, stream>>>(item_embed, user_embed, offs + NU, csr,
                                         W_self, W_neigh, bias, item_out, NI);
}

// Round 6
// 1655.812 us; speedup vs baseline: 2.0299x; 1.2530x over previous
//
#include <hip/hip_runtime.h>

#define D 32
#define RBC 4096          // rows per coarse bucket (12-bit local row)
#define RBC_SHIFT 12
#define CAP 32            // staged entries per bucket per block
#define MAXNC 512         // max coarse buckets (N2 <= 2M)

// ---------------------------------------------------------------------------
__global__ __launch_bounds__(256) void zero_i32(int* __restrict__ p, int n) {
    int i = blockIdx.x * blockDim.x + threadIdx.x;
    int stride = gridDim.x * blockDim.x;
    for (; i < n; i += stride) p[i] = 0;
}

// ---------------------------------------------------------------------------
// coarse-bucket histogram of entries (2 per edge), LDS-binned
// ---------------------------------------------------------------------------
__global__ __launch_bounds__(256) void bucket_hist(
        const int* __restrict__ src, const int* __restrict__ dst,
        int* __restrict__ bcnt, int NU, int E) {
    __shared__ int h[MAXNC];
    for (int i = threadIdx.x; i < MAXNC; i += 256) h[i] = 0;
    __syncthreads();
    int i = blockIdx.x * 256 + threadIdx.x;
    int stride = gridDim.x * 256;
    for (; i < E; i += stride) {
        int s = src[i];
        int d = dst[i];
        atomicAdd(&h[s >> RBC_SHIFT], 1);
        atomicAdd(&h[(NU + d) >> RBC_SHIFT], 1);
    }
    __syncthreads();
    for (int j = threadIdx.x; j < MAXNC; j += 256)
        if (h[j]) atomicAdd(&bcnt[j], h[j]);
}

// ---------------------------------------------------------------------------
// one-block scan over <=512 bucket counts producing BOTH:
//   boffsA/gcur: 16-entry-ALIGNED ents windows (for full-line staged flushes)
//   coffs:       EXACT csr windows (gapless global CSR)
// ---------------------------------------------------------------------------
__global__ __launch_bounds__(MAXNC) void scan_buckets(
        const int* __restrict__ bcnt, int* __restrict__ boffsA,
        int* __restrict__ gcur, int* __restrict__ coffs, int nbk) {
    __shared__ int sa[MAXNC], se[MAXNC];
    int t = threadIdx.x;
    int c = (t < nbk) ? bcnt[t] : 0;
    int a = (c + 15) & ~15;
    sa[t] = a;
    se[t] = c;
    __syncthreads();
    for (int off = 1; off < MAXNC; off <<= 1) {
        int va = (t >= off) ? sa[t - off] : 0;
        int ve = (t >= off) ? se[t - off] : 0;
        __syncthreads();
        sa[t] += va;
        se[t] += ve;
        __syncthreads();
    }
    int pa = (t == 0) ? 0 : sa[t - 1];
    int pe = (t == 0) ? 0 : se[t - 1];
    if (t < nbk) {
        boffsA[t] = pa;
        gcur[t]   = pa;
        coffs[t]  = pe;
        if (t == nbk - 1) {
            boffsA[nbk] = sa[t];
            coffs[nbk]  = se[t];
        }
    }
}

// ---------------------------------------------------------------------------
// LDS line-staged multisplit partition. Each block stages CAP entries per
// bucket in LDS; full 16-entry (64B) aligned lines are flushed by a single
// thread -> every HBM line written whole, once. Remainders drained at end
// (contiguous per bucket). Entry = (rowLocal<<20) | nbrIdx.
// ---------------------------------------------------------------------------
__global__ __launch_bounds__(512) void partition(
        const int* __restrict__ src, const int* __restrict__ dst,
        int* __restrict__ gcur, unsigned int* __restrict__ ents,
        int NU, int E, int nbk) {
    __shared__ unsigned int stage[MAXNC * CAP];   // 64 KB
    __shared__ int lcnt[MAXNC];
    int t = threadIdx.x;
    lcnt[t] = 0;
    __syncthreads();

    long per = ((long)E + gridDim.x - 1) / gridDim.x;
    long i0 = (long)blockIdx.x * per;
    long i1 = i0 + per;
    if (i1 > E) i1 = E;
    int nrounds = (i1 > i0) ? (int)((i1 - i0 + 511) >> 9) : 0;

    long i = i0 + t;
    int cs = 0, cd = 0;
    bool cv = (nrounds > 0) && (i < i1);
    if (cv) { cs = src[i]; cd = dst[i]; }

    for (int r = 0; r < nrounds; ++r) {
        long nx = i + 512;
        int ns = 0, nd = 0;
        bool nv = (nx < i1);
        if (nv) { ns = src[nx]; nd = dst[nx]; }   // prefetch next round

        if (cv) {
            // user row cs aggregates item cd
            int c1 = cs >> RBC_SHIFT;
            unsigned e1 = ((unsigned)(cs & (RBC - 1)) << 20) | (unsigned)cd;
            int p1 = atomicAdd(&lcnt[c1], 1);
            if (p1 < CAP) stage[(c1 << 5) + p1] = e1;
            else ents[atomicAdd(&gcur[c1], 1)] = e1;   // rare overflow
            // item row NU+cd aggregates user cs
            int r2 = NU + cd;
            int c2 = r2 >> RBC_SHIFT;
            unsigned e2 = ((unsigned)(r2 & (RBC - 1)) << 20) | (unsigned)cs;
            int p2 = atomicAdd(&lcnt[c2], 1);
            if (p2 < CAP) stage[(c2 << 5) + p2] = e2;
            else ents[atomicAdd(&gcur[c2], 1)] = e2;
        }
        __syncthreads();

        // flush full 64B lines; thread t owns bucket t
        if (t < nbk) {
            int cnt = lcnt[t];
            if (cnt > CAP) cnt = CAP;
            int nf = (cnt >= 16) ? (cnt & ~15) : 0;
            if (nf) {
                int g = atomicAdd(&gcur[t], nf);   // g stays 16-aligned
#pragma unroll
                for (int k = 0; k < CAP; k += 4) {
                    if (k < nf) {
                        uint4 w = *(uint4*)&stage[(t << 5) + k];
                        *(uint4*)&ents[g + k] = w;
                    }
                }
                for (int k = 0; k < cnt - nf; ++k)
                    stage[(t << 5) + k] = stage[(t << 5) + nf + k];
            }
            lcnt[t] = cnt - nf;
        }
        __syncthreads();
        cs = ns; cd = nd; cv = nv; i = nx;
    }

    // drain remainders (contiguous chunks per bucket)
    if (t < nbk) {
        int cnt = lcnt[t];
        if (cnt > CAP) cnt = CAP;
        if (cnt > 0) {
            int g = atomicAdd(&gcur[t], cnt);
            for (int k = 0; k < cnt; ++k) ents[g + k] = stage[(t << 5) + k];
        }
    }
}

// ---------------------------------------------------------------------------
// block-local counting sort: one block per coarse bucket (4096 rows).
// Reads its ents window, emits gapless global CSR + exact per-row offs.
// ---------------------------------------------------------------------------
__global__ __launch_bounds__(512) void local_sort(
        const unsigned int* __restrict__ ents, const int* __restrict__ boffsA,
        const int* __restrict__ bcnt, const int* __restrict__ coffs,
        int* __restrict__ csr, int* __restrict__ offs, long N2, int nbk) {
    __shared__ int cnt[RBC];
    __shared__ int cur[RBC];
    __shared__ int tsum[512];
    int b = blockIdx.x, t = threadIdx.x;
    int e0 = boffsA[b];
    int n  = bcnt[b];
    int c0 = coffs[b];

    for (int j = t; j < RBC; j += 512) cnt[j] = 0;
    __syncthreads();
    for (int k = t; k < n; k += 512)
        atomicAdd(&cnt[ents[e0 + k] >> 20], 1);
    __syncthreads();

    // thread t owns bins [8t, 8t+8)
    int x[8], pre[8], sum = 0;
#pragma unroll
    for (int j = 0; j < 8; ++j) {
        x[j] = cnt[t * 8 + j];
        pre[j] = sum;
        sum += x[j];
    }
    tsum[t] = sum;
    __syncthreads();
    for (int off = 1; off < 512; off <<= 1) {
        int v = (t >= off) ? tsum[t - off] : 0;
        __syncthreads();
        tsum[t] += v;
        __syncthreads();
    }
    int p = (t == 0) ? 0 : tsum[t - 1];
    long rowbase = (long)b << RBC_SHIFT;
#pragma unroll
    for (int j = 0; j < 8; ++j) {
        int o = p + pre[j];
        cur[t * 8 + j] = o;
        long row = rowbase + t * 8 + j;
        if (row < N2) offs[row] = c0 + o;   // exact, gapless across buckets
    }
    if (b == nbk - 1 && t == 0) offs[N2] = c0 + n;
    __syncthreads();

    for (int k = t; k < n; k += 512) {
        unsigned en = ents[e0 + k];
        int rl = (int)(en >> 20);
        int pos = atomicAdd(&cur[rl], 1);
        csr[c0 + pos] = (int)(en & 0xFFFFFu);
    }
}

// ---------------------------------------------------------------------------
// one phase of fused aggregate + SAGE transform (unchanged from round 5)
// ---------------------------------------------------------------------------
__global__ __launch_bounds__(256, 8) void sage_phase(
        const float* __restrict__ self_embed,
        const float* __restrict__ nbr_embed,
        const int* __restrict__ offs,      // [N+1], pre-offset for this phase
        const int* __restrict__ csr,
        const float* __restrict__ Wself, const float* __restrict__ Wneigh,
        const float* __restrict__ bias,
        float* __restrict__ out, int N) {
    __shared__ float sWs[D * D];
    __shared__ float sWn[D * D];
    __shared__ float sb[D];
    for (int i = threadIdx.x; i < D * D; i += blockDim.x) {
        sWs[i] = Wself[i];
        sWn[i] = Wneigh[i];
    }
    if (threadIdx.x < D) sb[threadIdx.x] = bias[threadIdx.x];
    __syncthreads();

    int lane = threadIdx.x & 31;
    long g  = ((long)blockIdx.x * blockDim.x + threadIdx.x) >> 5;
    long ng = ((long)gridDim.x * blockDim.x) >> 5;

    for (long row = g; row < N; row += ng) {
        int o0 = offs[row];
        int o1 = offs[row + 1];
        int deg = o1 - o0;
        float s = 0.f;
        for (int j0 = o0; j0 < o1; j0 += 32) {
            int nb = o1 - j0;
            if (nb > 32) nb = 32;
            int idx = csr[j0 + (lane < nb ? lane : nb - 1)];
            for (int k = 0; k < nb; k += 8) {
                int kr = nb - k;  // >= 1
                float v[8];
#pragma unroll
                for (int u = 0; u < 8; ++u) {
                    int uu = u < kr ? u : kr - 1;   // clamp (dup loads cache-hit)
                    int bi = __shfl(idx, k + uu, 32);
                    v[u] = nbr_embed[(long)bi * D + lane];
                }
#pragma unroll
                for (int u = 0; u < 8; ++u) {
                    s += (u < kr) ? v[u] : 0.f;
                }
            }
        }
        float m = s / fmaxf((float)deg, 1.0f);
        float e = self_embed[row * D + lane];
        float acc = sb[lane];
#pragma unroll
        for (int k = 0; k < D; ++k) {
            acc += __shfl(e, k, 32) * sWs[k * D + lane]
                 + __shfl(m, k, 32) * sWn[k * D + lane];
        }
        out[row * D + lane] = acc;
    }
}

// ---------------------------------------------------------------------------
extern "C" void kernel_launch(void* const* d_in, const int* in_sizes, int n_in,
                              void* d_out, int out_size, void* d_ws, size_t ws_size,
                              hipStream_t stream) {
    const float* user_embed = (const float*)d_in[0];
    const float* item_embed = (const float*)d_in[1];
    const float* W_self     = (const float*)d_in[2];
    const float* W_neigh    = (const float*)d_in[3];
    const float* bias       = (const float*)d_in[4];
    const int*   edge_src   = (const int*)d_in[5];
    const int*   edge_dst   = (const int*)d_in[6];

    const int NU = in_sizes[0] / D;
    const int NI = in_sizes[1] / D;
    const int E  = in_sizes[5];
    const long N2 = (long)NU + NI;
    const int nbk = (int)((N2 + RBC - 1) >> RBC_SHIFT);   // 489 for 2M rows

    float* user_out = (float*)d_out;            // [NU*D]
    float* item_out = user_out + (long)NU * D;  // [NI*D]

    // workspace layout (int units, 16B-aligned where vector stores need it):
    // offs[N2+1] | bcnt[nbk] | boffsA[nbk+1] | gcur[nbk] | coffs[nbk+1] |
    // ents[2E + 15*nbk] | csr[2E]
    long p = 0;
    int* offs   = (int*)d_ws + p;  p += N2 + 1;   p = (p + 3) & ~3L;
    int* bcnt   = (int*)d_ws + p;  p += nbk;
    int* boffsA = (int*)d_ws + p;  p += nbk + 1;
    int* gcur   = (int*)d_ws + p;  p += nbk;
    int* coffs  = (int*)d_ws + p;  p += nbk + 1;  p = (p + 3) & ~3L;
    unsigned int* ents = (unsigned int*)((int*)d_ws + p);
    p += 2L * E + 15L * nbk;       p = (p + 3) & ~3L;
    int* csr    = (int*)d_ws + p;

    // 1) zero coarse-bucket counts
    zero_i32<<<2, 256, 0, stream>>>(bcnt, nbk);

    // 2) coarse histogram
    bucket_hist<<<512, 256, 0, stream>>>(edge_src, edge_dst, bcnt, NU, E);

    // 3) dual scan: aligned ents windows + exact csr windows
    scan_buckets<<<1, MAXNC, 0, stream>>>(bcnt, boffsA, gcur, coffs, nbk);

    // 4) line-staged multisplit partition (full-line HBM writes)
    partition<<<512, 512, 0, stream>>>(edge_src, edge_dst, gcur, ents, NU, E, nbk);

    // 5) per-bucket counting sort -> gapless CSR + exact per-row offs
    local_sort<<<nbk, 512, 0, stream>>>(ents, boffsA, bcnt, coffs, csr, offs,
                                        N2, nbk);

    // 6) fused gather-mean + SAGE transform, phase-split for L3 residency
    sage_phase<<<2048, 256, 0, stream>>>(user_embed, item_embed, offs, csr,
                                         W_self, W_neigh, bias, user_out, NU);
    sage_phase<<<2048, 256, 0, stream>>>(item_embed, user_embed, offs + NU, csr,
                                         W_self, W_neigh, bias, item_out, NI);
}